// Round 7
// baseline (112.640 us; speedup 1.0000x reference)
//
#include <hip/hip_runtime.h>

// FAVOR+ causal linear attention — fused kernel, relaxed grid barrier, sc1
// (MALL) for cross-barrier data. Grid = 512 blocks x 256 thr, 1 chunk (C=32)
// per block, 30.5 KB LDS -> 2 blocks/CU (8 waves/CU, 2/SIMD).
// Phase A: phiQ^T(LDS), phiK^T(LDS), phiK(LDS), S_c^T->ws(sc1), z_c->ws(sc1),
//          masked Amat(LDS), norm_intra(LDS), Y_intra -> registers.
// gbar -> Phase B: exclusive prefix scan of S^T (uint cols) + z over chunks.
// gbar -> Phase C: acc += phiQ^T.S_excl; out = acc / (normI + phiQ^T.z_excl).

#define BH 8
#define DD 64
#define DV 64
#define NSEQ 2048
#define MM 128
#define CK 32
#define NCH 64
#define NBLK 512
#define PHI_SCALE 0.08838834764831845f

typedef unsigned int uint;
typedef unsigned short ushort;
typedef unsigned long long ulong64;
typedef __attribute__((ext_vector_type(8))) short bf16x8;
typedef __attribute__((ext_vector_type(4))) float f32x4;
#define MFMA16(a, b, c) __builtin_amdgcn_mfma_f32_16x16x32_bf16((a), (b), (c), 0, 0, 0)

__device__ __forceinline__ short f2bf(float x) {
    uint u = __float_as_uint(x);
    u += 0x7fffu + ((u >> 16) & 1u);
    return (short)(u >> 16);
}
__device__ __forceinline__ float bf2f(ushort b) {
    return __uint_as_float(((uint)b) << 16);
}

#define AST(p, v)  __hip_atomic_store((p), (v), __ATOMIC_RELAXED, __HIP_MEMORY_SCOPE_AGENT)
#define ALD(p)     __hip_atomic_load((p), __ATOMIC_RELAXED, __HIP_MEMORY_SCOPE_AGENT)

// ws layout: St bf16 [BH][NCH][64][128] 8MB | z f32 [BH][NCH][128] 256KB | bar
#define OFF_Z   8388608u
#define OFF_BAR 8650752u

// relaxed grid barrier: no cache-flush fences. sc1 data ordering comes from
// __syncthreads' vmcnt(0) drain (stores complete at MALL before arrival add).
__device__ __forceinline__ void gbar(uint* cnt)
{
    __syncthreads();
    if (threadIdx.x == 0) {
        __hip_atomic_fetch_add(cnt, 1u, __ATOMIC_RELAXED, __HIP_MEMORY_SCOPE_AGENT);
        while (__hip_atomic_load(cnt, __ATOMIC_RELAXED, __HIP_MEMORY_SCOPE_AGENT) < NBLK)
            __builtin_amdgcn_s_sleep(4);
    }
    __syncthreads();
}

__global__ __launch_bounds__(256, 2) void favor_main(
    const float* __restrict__ keys, const float* __restrict__ values,
    const float* __restrict__ queries, const float* __restrict__ features,
    ushort* St, float* z, uint* bar, float* __restrict__ out)
{
    const int b = blockIdx.x;                    // 512 blocks = BH * NCH
    const int bh = b >> 6, ck = b & 63, n0c = ck * CK;
    const int tid = threadIdx.x;
    const int lane = tid & 63, wid = tid >> 6, quad = lane >> 4, l16 = lane & 15;

    __shared__ __align__(16) char sm[30464];
    short* sPQT = (short*)sm;                    // [32][136] bf16 PERSISTS  8704
    short* sPKT = (short*)(sm + 8704);           // [32][136] bf16 phase A   8704
    short* sPK  = (short*)(sm + 17408);          // [128][40] bf16 phase A  10240
    short* sAm  = (short*)(sm + 27648);          // [32][40]  bf16 phase A   2560
    float* sNI  = (float*)(sm + 30208);          // [2][32] f32 PERSISTS      256
    // phase-C aliases (sPKT/sPK/sAm dead after Y):
    float* sOut = (float*)(sm + 8704);           // [32][66] f32             8448
    float* sPart= (float*)(sm + 17408);          // [32][4]  f32              512
    float* sNm  = (float*)(sm + 17920);          // [32]     f32              128
    float* sZ   = (float*)(sm + 18048);          // [128]    f32              512

    // ---- Phase A ----
    // zero Amat (upper-triangle tiles stay 0) and both sNI slots
    for (int i = tid; i < 640; i += 256) ((uint*)sAm)[i] = 0u;
    if (tid < 64) sNI[tid] = 0.f;

    // phi stage: wave = (sw = n-subtile, mh = m-half). 8 MFMAs/wave.
    {
        const int sw = wid & 1, mh = wid >> 1;
        const float* Qb = queries + (size_t)(bh * DD) * NSEQ + n0c + 16 * sw + l16;
        const float* Kb = keys    + (size_t)(bh * DD) * NSEQ + n0c + 16 * sw + l16;
        bf16x8 aQ[2], aK[2];
        for (int h = 0; h < 2; ++h)
            for (int j = 0; j < 8; ++j) {
                const int d = 32 * h + 8 * quad + j;
                aQ[h][j] = f2bf(Qb[(size_t)d * NSEQ]);
                aK[h][j] = f2bf(Kb[(size_t)d * NSEQ]);
            }
        for (int t = 0; t < 4; ++t) {
            const int mt = 4 * mh + t;
            f32x4 accQ = {0.f, 0.f, 0.f, 0.f}, accK = {0.f, 0.f, 0.f, 0.f};
            for (int h = 0; h < 2; ++h) {
                const float4* fp = (const float4*)(features + (16 * mt + l16) * 64 + 32 * h + 8 * quad);
                float4 f0 = fp[0], f1 = fp[1];
                bf16x8 bF;
                bF[0] = f2bf(f0.x); bF[1] = f2bf(f0.y); bF[2] = f2bf(f0.z); bF[3] = f2bf(f0.w);
                bF[4] = f2bf(f1.x); bF[5] = f2bf(f1.y); bF[6] = f2bf(f1.z); bF[7] = f2bf(f1.w);
                accQ = MFMA16(aQ[h], bF, accQ);
                accK = MFMA16(aK[h], bF, accK);
            }
            for (int r = 0; r < 4; ++r) {
                const int nl = 16 * sw + 4 * quad + r, m = 16 * mt + l16;
                sPQT[nl * 136 + m] = f2bf(fmaxf(accQ[r], 0.f) * PHI_SCALE);
                const short pk = f2bf(fmaxf(accK[r], 0.f) * PHI_SCALE);
                sPKT[nl * 136 + m] = pk;
                sPK[m * 40 + nl] = pk;
            }
        }
    }
    __syncthreads();  // B0

    // z_c[m] = sum_n phiK[m][n] (sc1; rotated for banks)
    if (tid < 128) {
        const short* pp = sPK + tid * 40;
        float s = 0.f;
        for (int n = 0; n < CK; ++n) s += bf2f((ushort)pp[(n + tid) & 31]);
        AST(&z[(size_t)(bh * NCH + ck) * MM + tid], s);
    }

    // S_c^T[v][m] = sum_n V[v][n] phiK[m][n]; wave = v-tile. 8 MFMAs/wave.
    {
        const int vt = wid;
        ushort* So = St + (size_t)(bh * NCH + ck) * (DV * MM);
        const float4* vp = (const float4*)(values + (size_t)(bh * DV + 16 * vt + l16) * NSEQ
                                           + n0c + 8 * quad);
        float4 v0 = vp[0], v1 = vp[1];
        bf16x8 aV;
        aV[0] = f2bf(v0.x); aV[1] = f2bf(v0.y); aV[2] = f2bf(v0.z); aV[3] = f2bf(v0.w);
        aV[4] = f2bf(v1.x); aV[5] = f2bf(v1.y); aV[6] = f2bf(v1.z); aV[7] = f2bf(v1.w);
        for (int mt = 0; mt < 8; ++mt) {
            bf16x8 bP = *(const bf16x8*)(sPK + (16 * mt + l16) * 40 + 8 * quad);
            f32x4 acc = {0.f, 0.f, 0.f, 0.f};
            acc = MFMA16(aV, bP, acc);
            for (int r = 0; r < 4; ++r)
                AST(&So[(16 * vt + 4 * quad + r) * MM + 16 * mt + l16],
                    (ushort)f2bf(acc[r]));
        }
    }

    // Amat causal tiles: wave0 (0,0), wave1 (1,0), wave2 (1,1); wave3 idle.
    if (wid < 3) {
        const int swA = (wid >= 1) ? 1 : 0, jtA = (wid == 2) ? 1 : 0;
        f32x4 acc = {0.f, 0.f, 0.f, 0.f};
        for (int mc = 0; mc < 4; ++mc) {
            bf16x8 aP = *(const bf16x8*)(sPQT + (16 * swA + l16) * 136 + 32 * mc + 8 * quad);
            bf16x8 bP = *(const bf16x8*)(sPKT + (16 * jtA + l16) * 136 + 32 * mc + 8 * quad);
            acc = MFMA16(aP, bP, acc);
        }
        float rs[4];
        for (int r = 0; r < 4; ++r) {
            const int nl = 16 * swA + 4 * quad + r, jl = 16 * jtA + l16;
            const float av = (jl <= nl) ? acc[r] : 0.f;
            rs[r] = av;
            sAm[nl * 40 + jl] = f2bf(av);
        }
        for (int r = 0; r < 4; ++r) {
            float s = rs[r];
            s += __shfl_xor(s, 1); s += __shfl_xor(s, 2);
            s += __shfl_xor(s, 4); s += __shfl_xor(s, 8);
            // slot 0: waves 0,1 (disjoint rows); slot 1: wave 2 (rows 16-31)
            if (l16 == 0) sNI[((wid == 2) ? 32 : 0) + 16 * swA + 4 * quad + r] = s;
        }
    }
    __syncthreads();  // B1

    // Y_intra: wave tile (nt = wid&1, v-pair = wid>>1); 1 MFMA per tile (K=32).
    const int nt = wid & 1, vp2 = wid >> 1;
    f32x4 acc[2];
    {
        bf16x8 aA = *(const bf16x8*)(sAm + (16 * nt + l16) * 40 + 8 * quad);
        for (int t = 0; t < 2; ++t) {
            const int vt = 2 * vp2 + t;
            const float4* vv = (const float4*)(values + (size_t)(bh * DV + 16 * vt + l16) * NSEQ
                                               + n0c + 8 * quad);
            float4 v0 = vv[0], v1 = vv[1];
            bf16x8 bV;
            bV[0] = f2bf(v0.x); bV[1] = f2bf(v0.y); bV[2] = f2bf(v0.z); bV[3] = f2bf(v0.w);
            bV[4] = f2bf(v1.x); bV[5] = f2bf(v1.y); bV[6] = f2bf(v1.z); bV[7] = f2bf(v1.w);
            acc[t] = (f32x4){0.f, 0.f, 0.f, 0.f};
            acc[t] = MFMA16(aA, bV, acc[t]);
        }
    }

    // ---- Phase B: grid barrier, exclusive prefix scans (sc1) ----
    gbar(bar + 0);
    if (b < 128) {                       // 32768 uint columns of St
        const int gid = b * 256 + tid;
        const int sbh = gid >> 12, col = gid & 4095;
        uint* p = (uint*)St + (size_t)sbh * (NCH * 4096) + col;
        uint v[NCH];
        #pragma unroll
        for (int cc = 0; cc < NCH; ++cc) v[cc] = ALD(p + (size_t)cc * 4096);
        float rlo = 0.f, rhi = 0.f;
        #pragma unroll
        for (int cc = 0; cc < NCH; ++cc) {
            const uint ov = (uint)(ushort)f2bf(rlo) | ((uint)(ushort)f2bf(rhi) << 16);
            AST(p + (size_t)cc * 4096, ov);
            rlo += bf2f((ushort)(v[cc] & 0xffffu));
            rhi += bf2f((ushort)(v[cc] >> 16));
        }
    } else if (b < 132) {                // 1024 z columns
        const int zc = (b - 128) * 256 + tid;
        const int zbh = zc >> 7, m = zc & 127;
        float* pz = z + (size_t)zbh * (NCH * MM) + m;
        float zv[NCH];
        #pragma unroll
        for (int cc = 0; cc < NCH; ++cc) zv[cc] = ALD(pz + cc * MM);
        float zr = 0.f;
        #pragma unroll
        for (int cc = 0; cc < NCH; ++cc) {
            AST(pz + cc * MM, zr);
            zr += zv[cc];
        }
    }
    gbar(bar + 1);

    // ---- Phase C ----
    // stage z_excl to LDS (coalesced sc1)
    if (tid < 128) sZ[tid] = ALD(&z[(size_t)(bh * NCH + ck) * MM + tid]);
    // acc += phiQ^T . S_excl  (St frags via 8B sc1 loads); 8 MFMAs/wave
    {
        const ulong64* sb8 = (const ulong64*)(St + (size_t)(bh * NCH + ck) * 8192);
        bf16x8 aP[4];
        for (int mc = 0; mc < 4; ++mc)
            aP[mc] = *(const bf16x8*)(sPQT + (16 * nt + l16) * 136 + 32 * mc + 8 * quad);
        for (int t = 0; t < 2; ++t) {
            const int row = 16 * (2 * vp2 + t) + l16;
            for (int mc = 0; mc < 4; ++mc) {
                union { ulong64 u[2]; bf16x8 v; } cvt;
                cvt.u[0] = ALD(sb8 + row * 32 + 8 * mc + 2 * quad);
                cvt.u[1] = ALD(sb8 + row * 32 + 8 * mc + 2 * quad + 1);
                acc[t] = MFMA16(aP[mc], cvt.v, acc[t]);
            }
        }
    }
    __syncthreads();
    // norm matvec partials: phiQ^T (LDS) . z_excl (LDS)
    if (tid < 128) {
        const int n = tid >> 2, seg = tid & 3;
        const uint* pr2 = (const uint*)sPQT + n * 68 + seg * 16;
        const float* zz = sZ + seg * 32;
        float s = 0.f;
        #pragma unroll
        for (int k = 0; k < 16; ++k) {
            const uint u = pr2[k];
            s += bf2f((ushort)(u & 0xffffu)) * zz[2 * k];
            s += bf2f((ushort)(u >> 16)) * zz[2 * k + 1];
        }
        sPart[n * 4 + seg] = s;
    }
    __syncthreads();
    if (tid < 32) {
        float nm = sNI[tid] + sNI[32 + tid];
        #pragma unroll
        for (int s4 = 0; s4 < 4; ++s4) nm += sPart[tid * 4 + s4];
        sNm[tid] = nm;
    }
    __syncthreads();
    // divide + transpose-stage
    for (int t = 0; t < 2; ++t)
        for (int r = 0; r < 4; ++r) {
            const int nl = 16 * nt + 4 * quad + r, v = 16 * (2 * vp2 + t) + l16;
            sOut[nl * 66 + v] = acc[t][r] / sNm[nl];
        }
    __syncthreads();
    // coalesced store (lanes along n)
    for (int i = tid; i < 2048; i += 256) {
        const int v = i >> 5, n = i & 31;
        out[(size_t)(bh * DV + v) * NSEQ + n0c + n] = sOut[n * 66 + v];
    }
}

extern "C" void kernel_launch(void* const* d_in, const int* in_sizes, int n_in,
                              void* d_out, int out_size, void* d_ws, size_t ws_size,
                              hipStream_t stream)
{
    (void)in_sizes; (void)n_in; (void)out_size; (void)ws_size;
    const float* keys     = (const float*)d_in[0];
    const float* values   = (const float*)d_in[1];
    const float* queries  = (const float*)d_in[2];
    const float* features = (const float*)d_in[3];
    float* outp = (float*)d_out;

    char* ws = (char*)d_ws;
    ushort* St  = (ushort*)ws;
    float*  z   = (float*)(ws + OFF_Z);
    uint*   bar = (uint*)(ws + OFF_BAR);

    hipMemsetAsync(bar, 0, 8, stream);   // zero the two barrier counters
    favor_main<<<dim3(NBLK), dim3(256), 0, stream>>>(keys, values, queries,
                                                     features, St, z, bar, outp);
}